// Round 9
// baseline (84.439 us; speedup 1.0000x reference)
//
#include <hip/hip_runtime.h>
#include <hip/hip_bf16.h>

#define S_LEN  1024
#define BATCH  4
#define DMODEL 1024
#define NHEAD  16
#define DHEAD  64
#define NROWS  (S_LEN*BATCH)   // 4096

typedef __bf16 bf16;
typedef __bf16 bf16x2 __attribute__((ext_vector_type(2)));
typedef __bf16 bf16x4 __attribute__((ext_vector_type(4)));
typedef __bf16 bf16x8 __attribute__((ext_vector_type(8)));
typedef float  f32x4  __attribute__((ext_vector_type(4)));
typedef float  f32x16 __attribute__((ext_vector_type(16)));

#define AS1 __attribute__((address_space(1)))
#define AS3 __attribute__((address_space(3)))

#define QSCALE  0.18033688011112042f   // 0.125 * log2(e)

__device__ __forceinline__ void gload16(const bf16* g, bf16* l) {
  __builtin_amdgcn_global_load_lds((const AS1 void*)g, (AS3 void*)l, 16, 0, 0);
}

__device__ __forceinline__ float fast_exp2(float x) {
#if __has_builtin(__builtin_amdgcn_exp2f)
  return __builtin_amdgcn_exp2f(x);
#else
  return exp2f(x);
#endif
}

// ---------------- fused fp32 -> bf16 convert ----------------
__global__ __launch_bounds__(256) void cvt_all(
    const float* __restrict__ hs, const float* __restrict__ wq,
    const float* __restrict__ wk, const float* __restrict__ wv,
    bf16* __restrict__ Xb, bf16* __restrict__ Wb)
{
  const int b = blockIdx.x;
  const float* src; bf16* dst; int i;
  if (b < 2048)      { src = hs; dst = Xb;                           i = b*256        + threadIdx.x; }
  else if (b < 2560) { src = wq; dst = Wb;                           i = (b-2048)*256 + threadIdx.x; }
  else if (b < 3072) { src = wk; dst = Wb + (size_t)DMODEL*DMODEL;   i = (b-2560)*256 + threadIdx.x; }
  else               { src = wv; dst = Wb + (size_t)2*DMODEL*DMODEL; i = (b-3072)*256 + threadIdx.x; }
  const float4* s4 = (const float4*)src;
  float4 a = s4[2*i], c = s4[2*i+1];
  bf16x8 o;
  o[0]=(bf16)a.x; o[1]=(bf16)a.y; o[2]=(bf16)a.z; o[3]=(bf16)a.w;
  o[4]=(bf16)c.x; o[5]=(bf16)c.y; o[6]=(bf16)c.z; o[7]=(bf16)c.w;
  ((bf16x8*)dst)[i] = o;
}

// ---------------- fused QKV GEMM, m97 structure (unchanged) ----------------
#define BM 128
#define BN 128
#define BK 32

__global__ __launch_bounds__(256) void qkv_gemm(
    const bf16* __restrict__ X, const bf16* __restrict__ Wcat,
    const float* __restrict__ bq, const float* __restrict__ bk, const float* __restrict__ bv,
    bf16* __restrict__ Qo, bf16* __restrict__ Ko, bf16* __restrict__ Vo)
{
  __shared__ __align__(16) bf16 As[BM*BK];
  __shared__ __align__(16) bf16 Bs[BN*BK];

  const int tid  = threadIdx.x;
  const int row0 = blockIdx.x * BM;
  const int col0 = blockIdx.y * BN;
  const int wsel = col0 >> 10;
  const int coln = col0 & 1023;

  const int wv   = tid >> 6;
  const int lane = tid & 63;
  const int lg   = lane >> 4;
  const int lr   = lane & 15;
  const int wr   = (wv >> 1) << 6;
  const int wc   = (wv & 1) << 6;

  const int c0 = tid, c1 = tid + 256;
  const size_t gA0 = (size_t)(row0 + (c0>>2))*DMODEL + (size_t)((c0&3)<<3);
  const size_t gA1 = (size_t)(row0 + (c1>>2))*DMODEL + (size_t)((c1&3)<<3);
  const size_t gB0 = (size_t)(col0 + (c0>>2))*DMODEL + (size_t)((c0&3)<<3);
  const size_t gB1 = (size_t)(col0 + (c1>>2))*DMODEL + (size_t)((c1&3)<<3);
  const int wb = (tid >> 6) << 6;
  bf16* lA0 = As + (size_t)wb*8;
  bf16* lA1 = As + (size_t)(wb+256)*8;
  bf16* lB0 = Bs + (size_t)wb*8;
  bf16* lB1 = Bs + (size_t)(wb+256)*8;

  f32x4 acc[4][4];
  #pragma unroll
  for (int mi=0; mi<4; ++mi)
    #pragma unroll
    for (int ni=0; ni<4; ++ni)
      acc[mi][ni] = (f32x4){0.f,0.f,0.f,0.f};

  for (int k0 = 0; k0 < DMODEL; k0 += BK) {
    __syncthreads();
    gload16(X    + gA0 + k0, lA0);
    gload16(X    + gA1 + k0, lA1);
    gload16(Wcat + gB0 + k0, lB0);
    gload16(Wcat + gB1 + k0, lB1);
    __syncthreads();

    bf16x8 af[4], bfr[4];
    #pragma unroll
    for (int mi=0; mi<4; ++mi)
      af[mi] = *(const bf16x8*)&As[(wr + mi*16 + lr)*BK + lg*8];
    #pragma unroll
    for (int ni=0; ni<4; ++ni)
      bfr[ni] = *(const bf16x8*)&Bs[(wc + ni*16 + lr)*BK + lg*8];

    #pragma unroll
    for (int mi=0; mi<4; ++mi)
      #pragma unroll
      for (int ni=0; ni<4; ++ni)
        acc[mi][ni] = __builtin_amdgcn_mfma_f32_16x16x32_bf16(af[mi], bfr[ni], acc[mi][ni], 0, 0, 0);
  }

  const float* bias = (wsel==0) ? bq : ((wsel==1) ? bk : bv);
  bf16* Out = (wsel==0) ? Qo : ((wsel==1) ? Ko : Vo);
  const float oscale = (wsel==0) ? QSCALE : 1.0f;

  #pragma unroll
  for (int ni=0; ni<4; ++ni) {
    const int co = coln + wc + ni*16 + lr;
    const float bias_v = bias[co];
    const int h  = co >> 6;
    const int dh = co & 63;
    #pragma unroll
    for (int mi=0; mi<4; ++mi) {
      #pragma unroll
      for (int p=0; p<4; ++p) {
        const int gr = row0 + wr + mi*16 + lg*4 + p;
        const int s_ = gr >> 2;
        const int b_ = gr & 3;
        Out[((size_t)(b_*NHEAD + h)*S_LEN + s_)*DHEAD + dh] = (bf16)((acc[mi][ni][p] + bias_v) * oscale);
      }
    }
  }
}

// ---------------- MFMA flash attention: K-split x2, 8 waves, 4 waves/SIMD ----------------
// 2 groups of 4 waves; group g sweeps t in [512g, 512g+512) for the same 128 q-rows.
// 32x32 MFMA, swapped QK^T (D[t][q], q=lane&31), zero-shuffle P (k-slot relabeling),
// additive mask (exp2 underflow -> 0), XOR chunk-swizzled K / V^T tiles, dbuf,
// 1 barrier/tile. Epilogue: group 1 ctx+lsum -> LDS (retired K region), group 0 combines.
#define QBLK 128
#define KVB  64
#define LSWK(row, chunk) (((row)<<6) + ((((chunk) ^ ((row)&7)))<<3))

__global__ __launch_bounds__(512, 4) void attn_mfma(
    const bf16* __restrict__ Q, const bf16* __restrict__ K, const bf16* __restrict__ V,
    const float* __restrict__ mask, float* __restrict__ out)
{
  // layout: [0,32768) K tiles (2 groups x 2 bufs x 8KB)  | epilogue-reused as ctx exchange
  //         [32768,65536) V^T tiles | [65536,69632) mask | [69632,70656) lsumX | [70656,71168) Linv
  __shared__ __align__(16) char SM[71168];
  bf16*  KsG   = (bf16*)SM;
  bf16*  VtG   = (bf16*)(SM + 32768);
  float* Mskf  = (float*)(SM + 65536);
  float* lsumX = (float*)(SM + 69632);
  float* Linv  = (float*)(SM + 70656);
  float* Xch   = (float*)SM;

  const int bh   = blockIdx.x;
  const int b_   = bh >> 4;
  const int h_   = bh & 15;
  const int tid  = threadIdx.x;
  const int wv   = tid >> 6;             // 0..7
  const int g    = wv >> 2;              // k-half group
  const int wg   = wv & 3;               // wave within group
  const int lane = tid & 63;
  const int l31  = lane & 31;
  const int hh   = lane >> 5;
  const int q0   = blockIdx.y * QBLK;

  // ---- stage mask row once ----
  if (tid < 256) *(float4*)&Mskf[tid*4] = *(const float4*)&mask[(size_t)b_*S_LEN + tid*4];

  // ---- Q B-frags from global (pre-scaled by QSCALE): q = q0 + wg*32 + l31 ----
  const bf16* Qp = Q + ((size_t)bh*S_LEN + q0 + wg*32 + l31)*DHEAD;
  bf16x8 qb[4];
  #pragma unroll
  for (int dk=0; dk<4; ++dk) qb[dk] = *(const bf16x8*)&Qp[dk*16 + hh*8];

  const bf16* Kb = K + (size_t)bh*S_LEN*DHEAD;
  const bf16* Vb = V + (size_t)bh*S_LEN*DHEAD;

  // staging maps (256 threads per group)
  const int tid_g = tid & 255;
  const int krow = tid_g >> 2, kch = tid_g & 3;
  const int vrow = tid_g & 63, vcb = tid_g >> 6;
  const int tG0  = g * 512;

  // ---- prologue: stage group's tile 0 ----
  bf16x8 kr0 = *(const bf16x8*)&Kb[(size_t)(tG0+krow)*DHEAD + kch*8];
  bf16x8 kr1 = *(const bf16x8*)&Kb[(size_t)(tG0+krow)*DHEAD + kch*8 + 32];
  bf16x8 vr0 = *(const bf16x8*)&Vb[(size_t)(tG0+vrow)*DHEAD + vcb*16];
  bf16x8 vr1 = *(const bf16x8*)&Vb[(size_t)(tG0+vrow)*DHEAD + vcb*16 + 8];
  {
    bf16* Kn = KsG + (size_t)(g*2)*4096;
    bf16* Vn = VtG + (size_t)(g*2)*4096;
    *(bf16x8*)&Kn[LSWK(krow, kch)]   = kr0;
    *(bf16x8*)&Kn[LSWK(krow, kch+4)] = kr1;
    #pragma unroll
    for (int i=0;i<8;++i) {
      const int d0 = vcb*16 + i, d1 = d0 + 8;
      Vn[(d0<<6) + (((vrow>>3) ^ (d0&7))<<3) + (vrow&7)] = vr0[i];
      Vn[(d1<<6) + (((vrow>>3) ^ (d1&7))<<3) + (vrow&7)] = vr1[i];
    }
  }
  __syncthreads();

  f32x16 ctx[2];
  ctx[0] = (f32x16)0.f; ctx[1] = (f32x16)0.f;
  float lsum = 0.f;

  for (int t = 0; t < 8; ++t) {
    const bf16* Kc = KsG + (size_t)(g*2 + (t&1))*4096;
    const bf16* Vc = VtG + (size_t)(g*2 + (t&1))*4096;

    if (t < 7) {
      const size_t nb = (size_t)tG0 + (size_t)(t+1)*KVB;
      kr0 = *(const bf16x8*)&Kb[(nb+krow)*DHEAD + kch*8];
      kr1 = *(const bf16x8*)&Kb[(nb+krow)*DHEAD + kch*8 + 32];
      vr0 = *(const bf16x8*)&Vb[(nb+vrow)*DHEAD + vcb*16];
      vr1 = *(const bf16x8*)&Vb[(nb+vrow)*DHEAD + vcb*16 + 8];
    }

    const int tb = tG0 + t*KVB;
    #pragma unroll
    for (int t2=0; t2<2; ++t2) {
      // ---- QK^T (swapped): D[t][q] for one 32-t subtile ----
      f32x16 sacc = (f32x16)0.f;
      const int row = t2*32 + l31;
      __builtin_amdgcn_s_setprio(1);
      #pragma unroll
      for (int dk=0; dk<4; ++dk) {
        bf16x8 ka = *(const bf16x8*)&Kc[LSWK(row, dk*2 + hh)];
        sacc = __builtin_amdgcn_mfma_f32_32x32x16_bf16(ka, qb[dk], sacc, 0,0,0);
      }
      __builtin_amdgcn_s_setprio(0);

      // ---- softmax: p = exp2(s + m); pack to PV A-frags in-lane ----
      f32x4 mv[4];
      #pragma unroll
      for (int g4=0; g4<4; ++g4)
        mv[g4] = *(const f32x4*)&Mskf[tb + t2*32 + 8*g4 + 4*hh];
      float pe[16];
      #pragma unroll
      for (int e=0; e<16; ++e) {
        pe[e] = fast_exp2(sacc[e] + mv[e>>2][e&3]);
        lsum += pe[e];
      }
      bf16x8 pf[2];
      {
        union { bf16x2 h2[8]; bf16x8 v[2]; } u;
        #pragma unroll
        for (int j=0; j<8; ++j) { bf16x2 p2; p2[0]=(bf16)pe[2*j]; p2[1]=(bf16)pe[2*j+1]; u.h2[j]=p2; }
        pf[0] = u.v[0]; pf[1] = u.v[1];
      }

      // ---- PV for this subtile: B-frags via slot->t map (2x b64 each) ----
      __builtin_amdgcn_s_setprio(1);
      #pragma unroll
      for (int nt=0; nt<2; ++nt) {
        const int drow = nt*32 + l31;
        const int dbase = (drow<<6) + 4*hh;
        const int dsw = (drow&7);
        #pragma unroll
        for (int kk=0; kk<2; ++kk) {
          const int lc = t2*4 + kk*2;
          bf16x4 lo = *(const bf16x4*)&Vc[dbase + (((lc  ) ^ dsw)<<3)];
          bf16x4 hi = *(const bf16x4*)&Vc[dbase + (((lc+1) ^ dsw)<<3)];
          bf16x8 vb;
          #pragma unroll
          for (int j=0; j<4; ++j) { vb[j]=lo[j]; vb[4+j]=hi[j]; }
          ctx[nt] = __builtin_amdgcn_mfma_f32_32x32x16_bf16(pf[kk], vb, ctx[nt], 0,0,0);
        }
      }
      __builtin_amdgcn_s_setprio(0);
    }

    // ---- stage next tile into other buffer ----
    if (t < 7) {
      bf16* Kn = KsG + (size_t)(g*2 + ((t+1)&1))*4096;
      bf16* Vn = VtG + (size_t)(g*2 + ((t+1)&1))*4096;
      *(bf16x8*)&Kn[LSWK(krow, kch)]   = kr0;
      *(bf16x8*)&Kn[LSWK(krow, kch+4)] = kr1;
      #pragma unroll
      for (int i=0;i<8;++i) {
        const int d0 = vcb*16 + i, d1 = d0 + 8;
        Vn[(d0<<6) + (((vrow>>3) ^ (d0&7))<<3) + (vrow&7)] = vr0[i];
        Vn[(d1<<6) + (((vrow>>3) ^ (d1&7))<<3) + (vrow&7)] = vr1[i];
      }
    }
    __syncthreads();
  }

  // ---- combine the two k-halves ----
  float ls = lsum + __shfl_xor(lsum, 32);   // per-q (=l31) sum over this group's k-range

  if (g) {
    float* xc = Xch + (size_t)(wg*64 + lane)*32;
    #pragma unroll
    for (int ec=0; ec<8; ++ec) {
      f32x4 v;
      #pragma unroll
      for (int j=0; j<4; ++j) v[j] = (ec < 4) ? ctx[0][ec*4+j] : ctx[1][(ec-4)*4+j];
      *(f32x4*)&xc[((ec ^ (lane&7))<<2)] = v;
    }
    lsumX[wg*64 + lane] = ls;
  }
  __syncthreads();
  if (!g) {
    float* xc = Xch + (size_t)(wg*64 + lane)*32;
    #pragma unroll
    for (int ec=0; ec<8; ++ec) {
      f32x4 v = *(const f32x4*)&xc[((ec ^ (lane&7))<<2)];
      #pragma unroll
      for (int j=0; j<4; ++j) {
        if (ec < 4) ctx[0][ec*4+j] += v[j]; else ctx[1][(ec-4)*4+j] += v[j];
      }
    }
    ls += lsumX[wg*64 + lane];

    if (lane < 32) Linv[wg*32 + l31] = 1.f / ls;
    f32x4 inv4[4];
    #pragma unroll
    for (int g4=0; g4<4; ++g4) inv4[g4] = *(const f32x4*)&Linv[wg*32 + 8*g4 + 4*hh];

    float* op = out + ((size_t)(q0 + wg*32)*BATCH + b_)*DMODEL + h_*DHEAD + l31;
    #pragma unroll
    for (int e=0; e<16; ++e) {
      const int qe = (e&3) + 8*(e>>2) + 4*hh;
      const float inv = inv4[e>>2][e&3];
      float* oq = op + (size_t)qe*BATCH*DMODEL;
      oq[0]  = ctx[0][e] * inv;
      oq[32] = ctx[1][e] * inv;
    }
  }
}

// ---------------- launch ----------------
extern "C" void kernel_launch(void* const* d_in, const int* in_sizes, int n_in,
                              void* d_out, int out_size, void* d_ws, size_t ws_size,
                              hipStream_t stream) {
  const float* hs   = (const float*)d_in[0];
  const float* mask = (const float*)d_in[1];
  const float* Wq   = (const float*)d_in[2];
  const float* bq   = (const float*)d_in[3];
  const float* Wk   = (const float*)d_in[4];
  const float* bk   = (const float*)d_in[5];
  const float* Wv   = (const float*)d_in[6];
  const float* bv   = (const float*)d_in[7];
  float* out = (float*)d_out;

  char* ws = (char*)d_ws;
  bf16* Xb = (bf16*)ws;
  bf16* Wb = Xb + (size_t)NROWS*DMODEL;
  bf16* Qw = Wb + (size_t)3*DMODEL*DMODEL;
  bf16* Kw = Qw + (size_t)NROWS*DMODEL;
  bf16* Vw = Kw + (size_t)NROWS*DMODEL;

  cvt_all<<<3584, 256, 0, stream>>>(hs, Wq, Wk, Wv, Xb, Wb);

  qkv_gemm<<<dim3(NROWS/BM, 3*DMODEL/BN), 256, 0, stream>>>(Xb, Wb, bq, bk, bv, Qw, Kw, Vw);

  attn_mfma<<<dim3(BATCH*NHEAD, S_LEN/QBLK), 512, 0, stream>>>(Qw, Kw, Vw, mask, out);
}

// Round 10
// 80.823 us; speedup vs baseline: 1.0447x; 1.0447x over previous
//
#include <hip/hip_runtime.h>
#include <hip/hip_bf16.h>

#define S_LEN  1024
#define BATCH  4
#define DMODEL 1024
#define NHEAD  16
#define DHEAD  64
#define NROWS  (S_LEN*BATCH)   // 4096

typedef __bf16 bf16;
typedef __bf16 bf16x2 __attribute__((ext_vector_type(2)));
typedef __bf16 bf16x4 __attribute__((ext_vector_type(4)));
typedef __bf16 bf16x8 __attribute__((ext_vector_type(8)));
typedef float  f32x4  __attribute__((ext_vector_type(4)));
typedef float  f32x16 __attribute__((ext_vector_type(16)));

#define AS1 __attribute__((address_space(1)))
#define AS3 __attribute__((address_space(3)))

#define QSCALE  0.18033688011112042f   // 0.125 * log2(e)

__device__ __forceinline__ void gload16(const bf16* g, bf16* l) {
  __builtin_amdgcn_global_load_lds((const AS1 void*)g, (AS3 void*)l, 16, 0, 0);
}

__device__ __forceinline__ float fast_exp2(float x) {
#if __has_builtin(__builtin_amdgcn_exp2f)
  return __builtin_amdgcn_exp2f(x);
#else
  return exp2f(x);
#endif
}

// ---------------- fused fp32 -> bf16 convert + mask bitmask ----------------
__global__ __launch_bounds__(256) void cvt_all(
    const float* __restrict__ hs, const float* __restrict__ wq,
    const float* __restrict__ wk, const float* __restrict__ wv,
    const float* __restrict__ mask,
    bf16* __restrict__ Xb, bf16* __restrict__ Wb,
    unsigned long long* __restrict__ mbits)
{
  const int b = blockIdx.x;
  if (b == 3584) {   // mask -> per-tile 64-bit masked-position bitmask
    const int wv = threadIdx.x >> 6, lane = threadIdx.x & 63;
    #pragma unroll
    for (int t16 = 0; t16 < 16; ++t16) {
      const float v = mask[(size_t)wv*S_LEN + t16*64 + lane];
      const unsigned long long bal = __ballot(v < -1000.f);
      if (lane == 0) mbits[wv*16 + t16] = bal;
    }
    return;
  }
  const float* src; bf16* dst; int i;
  if (b < 2048)      { src = hs; dst = Xb;                           i = b*256        + threadIdx.x; }
  else if (b < 2560) { src = wq; dst = Wb;                           i = (b-2048)*256 + threadIdx.x; }
  else if (b < 3072) { src = wk; dst = Wb + (size_t)DMODEL*DMODEL;   i = (b-2560)*256 + threadIdx.x; }
  else               { src = wv; dst = Wb + (size_t)2*DMODEL*DMODEL; i = (b-3072)*256 + threadIdx.x; }
  const float4* s4 = (const float4*)src;
  float4 a = s4[2*i], c = s4[2*i+1];
  bf16x8 o;
  o[0]=(bf16)a.x; o[1]=(bf16)a.y; o[2]=(bf16)a.z; o[3]=(bf16)a.w;
  o[4]=(bf16)c.x; o[5]=(bf16)c.y; o[6]=(bf16)c.z; o[7]=(bf16)c.w;
  ((bf16x8*)dst)[i] = o;
}

// ---------------- fused QKV GEMM, m97 structure (unchanged) ----------------
#define BM 128
#define BN 128
#define BK 32

__global__ __launch_bounds__(256) void qkv_gemm(
    const bf16* __restrict__ X, const bf16* __restrict__ Wcat,
    const float* __restrict__ bq, const float* __restrict__ bk, const float* __restrict__ bv,
    bf16* __restrict__ Qo, bf16* __restrict__ Ko, bf16* __restrict__ Vo)
{
  __shared__ __align__(16) bf16 As[BM*BK];
  __shared__ __align__(16) bf16 Bs[BN*BK];

  const int tid  = threadIdx.x;
  const int row0 = blockIdx.x * BM;
  const int col0 = blockIdx.y * BN;
  const int wsel = col0 >> 10;
  const int coln = col0 & 1023;

  const int wv   = tid >> 6;
  const int lane = tid & 63;
  const int lg   = lane >> 4;
  const int lr   = lane & 15;
  const int wr   = (wv >> 1) << 6;
  const int wc   = (wv & 1) << 6;

  const int c0 = tid, c1 = tid + 256;
  const size_t gA0 = (size_t)(row0 + (c0>>2))*DMODEL + (size_t)((c0&3)<<3);
  const size_t gA1 = (size_t)(row0 + (c1>>2))*DMODEL + (size_t)((c1&3)<<3);
  const size_t gB0 = (size_t)(col0 + (c0>>2))*DMODEL + (size_t)((c0&3)<<3);
  const size_t gB1 = (size_t)(col0 + (c1>>2))*DMODEL + (size_t)((c1&3)<<3);
  const int wb = (tid >> 6) << 6;
  bf16* lA0 = As + (size_t)wb*8;
  bf16* lA1 = As + (size_t)(wb+256)*8;
  bf16* lB0 = Bs + (size_t)wb*8;
  bf16* lB1 = Bs + (size_t)(wb+256)*8;

  f32x4 acc[4][4];
  #pragma unroll
  for (int mi=0; mi<4; ++mi)
    #pragma unroll
    for (int ni=0; ni<4; ++ni)
      acc[mi][ni] = (f32x4){0.f,0.f,0.f,0.f};

  for (int k0 = 0; k0 < DMODEL; k0 += BK) {
    __syncthreads();
    gload16(X    + gA0 + k0, lA0);
    gload16(X    + gA1 + k0, lA1);
    gload16(Wcat + gB0 + k0, lB0);
    gload16(Wcat + gB1 + k0, lB1);
    __syncthreads();

    bf16x8 af[4], bfr[4];
    #pragma unroll
    for (int mi=0; mi<4; ++mi)
      af[mi] = *(const bf16x8*)&As[(wr + mi*16 + lr)*BK + lg*8];
    #pragma unroll
    for (int ni=0; ni<4; ++ni)
      bfr[ni] = *(const bf16x8*)&Bs[(wc + ni*16 + lr)*BK + lg*8];

    #pragma unroll
    for (int mi=0; mi<4; ++mi)
      #pragma unroll
      for (int ni=0; ni<4; ++ni)
        acc[mi][ni] = __builtin_amdgcn_mfma_f32_16x16x32_bf16(af[mi], bfr[ni], acc[mi][ni], 0, 0, 0);
  }

  const float* bias = (wsel==0) ? bq : ((wsel==1) ? bk : bv);
  bf16* Out = (wsel==0) ? Qo : ((wsel==1) ? Ko : Vo);
  const float oscale = (wsel==0) ? QSCALE : 1.0f;

  #pragma unroll
  for (int ni=0; ni<4; ++ni) {
    const int co = coln + wc + ni*16 + lr;
    const float bias_v = bias[co];
    const int h  = co >> 6;
    const int dh = co & 63;
    #pragma unroll
    for (int mi=0; mi<4; ++mi) {
      #pragma unroll
      for (int p=0; p<4; ++p) {
        const int gr = row0 + wr + mi*16 + lg*4 + p;
        const int s_ = gr >> 2;
        const int b_ = gr & 3;
        Out[((size_t)(b_*NHEAD + h)*S_LEN + s_)*DHEAD + dh] = (bf16)((acc[mi][ni][p] + bias_v) * oscale);
      }
    }
  }
}

// ---------------- V transpose: [B][H][S][64] -> [B][H][64][S] (done once) ----------------
__global__ __launch_bounds__(256) void vtrans(const bf16* __restrict__ V, bf16* __restrict__ VT)
{
  __shared__ bf16 Ts[64][72];
  const int bh = blockIdx.x;
  const int s0 = blockIdx.y * 64;
  const int tid = threadIdx.x;
  const int r = tid >> 2, c = (tid & 3) << 4;
  const bf16* src = V + ((size_t)bh*S_LEN + s0 + r)*DHEAD + c;
  *(bf16x8*)&Ts[r][c]     = *(const bf16x8*)src;
  *(bf16x8*)&Ts[r][c + 8] = *(const bf16x8*)(src + 8);
  __syncthreads();
  const int d = tid >> 2, sc = (tid & 3) << 4;
  bf16x8 o0, o1;
  #pragma unroll
  for (int i=0;i<8;++i) { o0[i] = Ts[sc+i][d]; o1[i] = Ts[sc+8+i][d]; }
  bf16* dst = VT + ((size_t)bh*DHEAD + d)*S_LEN + s0 + sc;
  *(bf16x8*)dst       = o0;
  *(bf16x8*)(dst + 8) = o1;
}

// ---------------- MFMA flash attention: 32x32, zero-shuffle P, DMA staging ----------------
// r7 structure (4 waves x 32 q, QBLK=128, KVB=64, dbuf, 1 barrier/tile) with:
//  - K and V^T staged by global_load_lds, source pre-swizzled so LDS image == r7's
//    (granule g = row*8+cs holds chunk cs^(row&7)); reads unchanged from r7.
//  - mask applied as per-tile 64-bit bitmask in registers (p = bit ? 0 : exp2(s)).
#define QBLK 128
#define KVB  64
#define LSWK(row, chunk) (((row)<<6) + ((((chunk) ^ ((row)&7)))<<3))

__global__ __launch_bounds__(256, 4) void attn_mfma(
    const bf16* __restrict__ Q, const bf16* __restrict__ K, const bf16* __restrict__ VT,
    const unsigned long long* __restrict__ mbits, float* __restrict__ out)
{
  __shared__ __align__(16) bf16 KsBuf[2][KVB*64];   // 16 KB
  __shared__ __align__(16) bf16 VtBuf[2][64*KVB];   // 16 KB
  __shared__ float Linv[4][32];                     // 512 B

  const int bh   = blockIdx.x;
  const int b_   = bh >> 4;
  const int h_   = bh & 15;
  const int tid  = threadIdx.x;
  const int wv   = tid >> 6;
  const int lane = tid & 63;
  const int l31  = lane & 31;
  const int hh   = lane >> 5;
  const int q0   = blockIdx.y * QBLK;

  // ---- Q B-frags from global (pre-scaled by QSCALE): q = lane&31 ----
  const bf16* Qp = Q + ((size_t)bh*S_LEN + q0 + wv*32 + l31)*DHEAD;
  bf16x8 qb[4];
  #pragma unroll
  for (int dk=0; dk<4; ++dk) qb[dk] = *(const bf16x8*)&Qp[dk*16 + hh*8];

  const bf16* Kb  = K  + (size_t)bh*S_LEN*DHEAD;
  const bf16* VTb = VT + (size_t)bh*DHEAD*S_LEN;
  const unsigned long long* mbp = mbits + (size_t)b_*16;

  // ---- DMA staging maps: lane writes granules g and g+256 (granule = 16B) ----
  // granule g = row*8 + cs must hold chunk cs^(row&7)  (matches LSWK reads)
  const int g0   = wv*64 + lane;
  const int row0_= g0 >> 3, cs0 = g0 & 7;
  const int ch0  = cs0 ^ (row0_ & 7);
  // +256 granules: row += 32, chunk unchanged (row&7 unchanged)
  const size_t koff0 = (size_t)row0_*DHEAD + ch0*8;
  const size_t koff1 = koff0 + (size_t)32*DHEAD;
  const size_t voff0 = (size_t)row0_*S_LEN + ch0*8;   // row0_ is d-row for V^T
  const size_t voff1 = voff0 + (size_t)32*S_LEN;
  bf16* kd0 = (bf16*)KsBuf[0];   // per-buffer bases resolved in loop
  bf16* vd0 = (bf16*)VtBuf[0];
  const int wdst0 = wv*512, wdst1 = wv*512 + 2048;   // elem offsets of wave's granule runs

  // ---- prologue: DMA tile 0 into buf 0 ----
  gload16(Kb  + koff0,  kd0 + wdst0);
  gload16(Kb  + koff1,  kd0 + wdst1);
  gload16(VTb + voff0,  vd0 + wdst0);
  gload16(VTb + voff1,  vd0 + wdst1);
  __syncthreads();

  f32x16 ctx[2];
  ctx[0] = (f32x16)0.f; ctx[1] = (f32x16)0.f;
  float lsum = 0.f;

  for (int t = 0; t < 16; ++t) {
    const bf16* Kc = KsBuf[t & 1];
    const bf16* Vc = VtBuf[t & 1];

    // ---- issue next tile's DMA early (overlaps compute below) ----
    if (t < 15) {
      const size_t nk = (size_t)(t+1)*KVB*DHEAD;   // K advance: 64 rows
      const size_t nv = (size_t)(t+1)*KVB;         // V^T advance: 64 t-cols
      bf16* kn = (bf16*)KsBuf[(t+1) & 1];
      bf16* vn = (bf16*)VtBuf[(t+1) & 1];
      gload16(Kb  + nk + koff0, kn + wdst0);
      gload16(Kb  + nk + koff1, kn + wdst1);
      gload16(VTb + nv + voff0, vn + wdst0);
      gload16(VTb + nv + voff1, vn + wdst1);
    }

    const unsigned long long mt = mbp[t];

    #pragma unroll
    for (int t2=0; t2<2; ++t2) {
      // ---- QK^T (swapped): D[t][q] for one 32-t subtile ----
      f32x16 sacc = (f32x16)0.f;
      const int row = t2*32 + l31;
      __builtin_amdgcn_s_setprio(1);
      #pragma unroll
      for (int dk=0; dk<4; ++dk) {
        bf16x8 ka = *(const bf16x8*)&Kc[LSWK(row, dk*2 + hh)];
        sacc = __builtin_amdgcn_mfma_f32_32x32x16_bf16(ka, qb[dk], sacc, 0,0,0);
      }
      __builtin_amdgcn_s_setprio(0);

      // ---- softmax: p = bit ? 0 : exp2(s); pack to PV A-frags in-lane ----
      const unsigned int mw = (unsigned int)(mt >> (t2*32 + 4*hh));
      float pe[16];
      #pragma unroll
      for (int e=0; e<16; ++e) {
        const float ex = fast_exp2(sacc[e]);
        pe[e] = ((mw >> ((e&3) + 8*(e>>2))) & 1u) ? 0.f : ex;
        lsum += pe[e];
      }
      bf16x8 pf[2];
      {
        union { bf16x2 h2[8]; bf16x8 v[2]; } u;
        #pragma unroll
        for (int j=0; j<8; ++j) { bf16x2 p2; p2[0]=(bf16)pe[2*j]; p2[1]=(bf16)pe[2*j+1]; u.h2[j]=p2; }
        pf[0] = u.v[0]; pf[1] = u.v[1];
      }

      // ---- PV: B-frags via slot->t map (2x b64 each), identical to r7 ----
      __builtin_amdgcn_s_setprio(1);
      #pragma unroll
      for (int nt=0; nt<2; ++nt) {
        const int drow = nt*32 + l31;
        const int dbase = (drow<<6) + 4*hh;
        const int dsw = (drow&7);
        #pragma unroll
        for (int kk=0; kk<2; ++kk) {
          const int lc = t2*4 + kk*2;
          bf16x4 lo = *(const bf16x4*)&Vc[dbase + (((lc  ) ^ dsw)<<3)];
          bf16x4 hi = *(const bf16x4*)&Vc[dbase + (((lc+1) ^ dsw)<<3)];
          bf16x8 vb;
          #pragma unroll
          for (int j=0; j<4; ++j) { vb[j]=lo[j]; vb[4+j]=hi[j]; }
          ctx[nt] = __builtin_amdgcn_mfma_f32_32x32x16_bf16(pf[kk], vb, ctx[nt], 0,0,0);
        }
      }
      __builtin_amdgcn_s_setprio(0);
    }

    __syncthreads();   // drains next-tile DMA (vmcnt) + all reads of cur buf done
  }

  // ---- lsum: partner-half add, distribute 1/lsum via per-wave LDS row ----
  const float tot = lsum + __shfl_xor(lsum, 32);
  if (lane < 32) Linv[wv][l31] = 1.f / tot;
  f32x4 inv4[4];
  #pragma unroll
  for (int g4=0; g4<4; ++g4) inv4[g4] = *(const f32x4*)&Linv[wv][8*g4 + 4*hh];

  // ---- write out: out[qg][b][h*64 + nt*32 + (lane&31)] ----
  float* op = out + ((size_t)(q0 + wv*32)*BATCH + b_)*DMODEL + h_*DHEAD + l31;
  #pragma unroll
  for (int e=0; e<16; ++e) {
    const int qe = (e&3) + 8*(e>>2) + 4*hh;
    const float inv = inv4[e>>2][e&3];
    float* oq = op + (size_t)qe*BATCH*DMODEL;
    oq[0]  = ctx[0][e] * inv;
    oq[32] = ctx[1][e] * inv;
  }
}

// ---------------- launch ----------------
extern "C" void kernel_launch(void* const* d_in, const int* in_sizes, int n_in,
                              void* d_out, int out_size, void* d_ws, size_t ws_size,
                              hipStream_t stream) {
  const float* hs   = (const float*)d_in[0];
  const float* mask = (const float*)d_in[1];
  const float* Wq   = (const float*)d_in[2];
  const float* bq   = (const float*)d_in[3];
  const float* Wk   = (const float*)d_in[4];
  const float* bk   = (const float*)d_in[5];
  const float* Wv   = (const float*)d_in[6];
  const float* bv   = (const float*)d_in[7];
  float* out = (float*)d_out;

  char* ws = (char*)d_ws;
  bf16* Xb = (bf16*)ws;                               // 8 MB; reused as VT after gemm
  bf16* Wb = Xb + (size_t)NROWS*DMODEL;               // 6 MB
  bf16* Qw = Wb + (size_t)3*DMODEL*DMODEL;            // 8 MB
  bf16* Kw = Qw + (size_t)NROWS*DMODEL;               // 8 MB
  bf16* Vw = Kw + (size_t)NROWS*DMODEL;               // 8 MB
  unsigned long long* Mb = (unsigned long long*)(Vw + (size_t)NROWS*DMODEL);  // 512 B
  bf16* VTw = Xb;   // alias: Xb dead after gemm; vtrans runs after gemm

  cvt_all<<<3585, 256, 0, stream>>>(hs, Wq, Wk, Wv, mask, Xb, Wb, Mb);

  qkv_gemm<<<dim3(NROWS/BM, 3*DMODEL/BN), 256, 0, stream>>>(Xb, Wb, bq, bk, bv, Qw, Kw, Vw);

  vtrans<<<dim3(BATCH*NHEAD, S_LEN/64), 256, 0, stream>>>(Vw, VTw);

  attn_mfma<<<dim3(BATCH*NHEAD, S_LEN/QBLK), 256, 0, stream>>>(Qw, Kw, VTw, Mb, out);
}